// Round 5
// baseline (559.368 us; speedup 1.0000x reference)
//
#include <hip/hip_runtime.h>
#include <math.h>

// Problem dims (fixed by the reference)
#define HDIM   2048
#define TWOH   4096
#define SEQLEN 8192
#define RCHUNK 32                 // rows per split-K chunk
#define NCHUNK (HDIM / RCHUNK)    // 64 chunks
#define C4     (TWOH / 4)         // 1024 float4 per row

// Algebra: scores_s = enc_s . (W^T hidden) + (b . hidden); the bias term is
// constant over s and drops out under softmax shift-invariance. So:
//   1) v = W^T hidden   (reads W, 33.5 MB)
//   2) scores = enc @ v (reads enc, 134 MB)
//   3) softmax(scores)  (fused into 2 via last-block pattern)
// Purely memory-bound: ~168 MB mandatory traffic.

// ---------------------------------------------------------------------------
// Kernel A: partial[chunk] = W[chunk rows]^T * hidden[chunk], float4-wide.
// Grid (4, 64), block 256. Also zeroes the completion counter for kernel C
// (A fully completes before C launches; kernel boundary = device visibility).
// ---------------------------------------------------------------------------
__global__ __launch_bounds__(256) void wtv_partial_kernel(
    const float4* __restrict__ W4, const float* __restrict__ hidden,
    float4* __restrict__ partial4, int* __restrict__ counter)
{
    __shared__ float hs[RCHUNK];
    const int tx = threadIdx.x;
    const int h0 = blockIdx.y * RCHUNK;
    if (tx < RCHUNK) hs[tx] = hidden[h0 + tx];
    __syncthreads();

    const int c = blockIdx.x * 256 + tx;     // float4 column, 0..1023
    float4 acc = {0.f, 0.f, 0.f, 0.f};
#pragma unroll 8
    for (int i = 0; i < RCHUNK; ++i) {
        const float4 w = W4[(size_t)(h0 + i) * C4 + c];
        const float  s = hs[i];
        acc.x = fmaf(w.x, s, acc.x);
        acc.y = fmaf(w.y, s, acc.y);
        acc.z = fmaf(w.z, s, acc.z);
        acc.w = fmaf(w.w, s, acc.w);
    }
    partial4[(size_t)blockIdx.y * C4 + c] = acc;

    if (tx == 0 && blockIdx.x == 0 && blockIdx.y == 0) *counter = 0;
}

// ---------------------------------------------------------------------------
// Kernel B: v = sum of 64 partials. Grid 4, block 256 (1024 float4 lanes).
// ---------------------------------------------------------------------------
__global__ __launch_bounds__(256) void wtv_reduce_kernel(
    const float4* __restrict__ partial4, float4* __restrict__ v4)
{
    const int c = blockIdx.x * 256 + threadIdx.x;
    float4 acc = {0.f, 0.f, 0.f, 0.f};
#pragma unroll
    for (int p = 0; p < NCHUNK; ++p) {
        const float4 t = partial4[(size_t)p * C4 + c];
        acc.x += t.x; acc.y += t.y; acc.z += t.z; acc.w += t.w;
    }
    v4[c] = acc;
}

// ---------------------------------------------------------------------------
// Kernel C: scores[r] = enc[r] . v  (one wave per row, v staged in LDS),
// then the LAST block (threadfence + atomic counter) runs the softmax.
// Grid 2048, block 256 (4 waves).
// ---------------------------------------------------------------------------
__global__ __launch_bounds__(256) void scores_softmax_kernel(
    const float4* __restrict__ enc4, const float4* __restrict__ v4,
    float* __restrict__ scores, int* __restrict__ counter,
    float* __restrict__ out)
{
    __shared__ float4 vs[C4];                  // 16 KiB
    const int tid = threadIdx.x;
    for (int i = tid; i < C4; i += 256) vs[i] = v4[i];
    __syncthreads();

    const int wave = tid >> 6;
    const int lane = tid & 63;
    const int r    = blockIdx.x * 4 + wave;    // 0..8191

    const float4* e4 = enc4 + (size_t)r * C4;
    float a0 = 0.f, a1 = 0.f;
#pragma unroll
    for (int i = 0; i < 16; i += 2) {          // 16*64 float4 = 4096 floats
        const float4 x0 = e4[i * 64 + lane];
        const float4 b0 = vs[i * 64 + lane];
        const float4 x1 = e4[(i + 1) * 64 + lane];
        const float4 b1 = vs[(i + 1) * 64 + lane];
        a0 += x0.x * b0.x + x0.y * b0.y + x0.z * b0.z + x0.w * b0.w;
        a1 += x1.x * b1.x + x1.y * b1.y + x1.z * b1.z + x1.w * b1.w;
    }
    float acc = a0 + a1;
#pragma unroll
    for (int off = 32; off > 0; off >>= 1)
        acc += __shfl_down(acc, off, 64);
    if (lane == 0) {
        scores[r] = acc;
        __threadfence();                       // release this wave's score
    }
    __syncthreads();

    __shared__ int amLast;
    if (tid == 0) {
        amLast = (atomicAdd(counter, 1) == (int)gridDim.x - 1);
        if (amLast) __threadfence();           // acquire side
    }
    __syncthreads();
    if (!amLast) return;

    // ---- last block only: softmax over scores[0..8191], 32 per thread ----
    float x[32];
    float m = -INFINITY;
#pragma unroll
    for (int i = 0; i < 32; ++i) {
        x[i] = scores[tid + i * 256];
        m = fmaxf(m, x[i]);
    }
#pragma unroll
    for (int off = 32; off > 0; off >>= 1)
        m = fmaxf(m, __shfl_xor(m, off, 64));
    __shared__ float red[4];
    if (lane == 0) red[wave] = m;
    __syncthreads();
    m = fmaxf(fmaxf(red[0], red[1]), fmaxf(red[2], red[3]));

    float s = 0.f;
#pragma unroll
    for (int i = 0; i < 32; ++i) {
        x[i] = expf(x[i] - m);
        s += x[i];
    }
#pragma unroll
    for (int off = 32; off > 0; off >>= 1)
        s += __shfl_xor(s, off, 64);
    __syncthreads();                           // before red[] reuse
    if (lane == 0) red[wave] = s;
    __syncthreads();
    s = red[0] + red[1] + red[2] + red[3];

    const float inv = 1.f / s;
#pragma unroll
    for (int i = 0; i < 32; ++i)
        out[tid + i * 256] = x[i] * inv;
}

// ---------------------------------------------------------------------------
extern "C" void kernel_launch(void* const* d_in, const int* in_sizes, int n_in,
                              void* d_out, int out_size, void* d_ws, size_t ws_size,
                              hipStream_t stream)
{
    const float* hidden = (const float*)d_in[0];   // [2048]
    const float* enc    = (const float*)d_in[1];   // [8192, 4096]
    const float* W      = (const float*)d_in[2];   // [2048, 4096]
    // d_in[3] = b : drops out under softmax shift-invariance

    float* ws      = (float*)d_ws;
    float* partial = ws;                            // 64 * 4096 floats (1 MiB)
    float* v       = partial + NCHUNK * TWOH;       // 4096
    float* scores  = v + TWOH;                      // 8192
    int*   counter = (int*)(scores + SEQLEN);       // 1 int
    float* out     = (float*)d_out;                 // [8192] fp32

    wtv_partial_kernel<<<dim3(4, NCHUNK), 256, 0, stream>>>(
        (const float4*)W, hidden, (float4*)partial, counter);
    wtv_reduce_kernel<<<4, 256, 0, stream>>>(
        (const float4*)partial, (float4*)v);
    scores_softmax_kernel<<<SEQLEN / 4, 256, 0, stream>>>(
        (const float4*)enc, (const float4*)v, scores, counter, out);
}

// Round 6
// 226.751 us; speedup vs baseline: 2.4669x; 2.4669x over previous
//
#include <hip/hip_runtime.h>
#include <math.h>

// Problem dims (fixed by the reference)
#define HDIM   2048
#define TWOH   4096
#define SEQLEN 8192
#define RCHUNK 32                 // rows per split-K chunk
#define NCHUNK (HDIM / RCHUNK)    // 64 chunks
#define C4     (TWOH / 4)         // 1024 float4 per row

// Algebra: scores_s = enc_s . (W^T hidden) + (b . hidden); the bias term is
// constant over s and drops out under softmax shift-invariance. So:
//   1) v = W^T hidden   (reads W, 33.5 MB)
//   2) scores = enc @ v (reads enc, 134 MB)
//   3) softmax(scores)  (separate tiny launch — NO device fences/atomics;
//      round-5 lesson: per-wave __threadfence = L2 writeback storm, 394 us)
// Purely memory-bound: ~168 MB mandatory traffic.

// ---------------------------------------------------------------------------
// Kernel A: partial[chunk] = W[chunk rows]^T * hidden[chunk], float4-wide.
// Grid (4, 64), block 256.
// ---------------------------------------------------------------------------
__global__ __launch_bounds__(256) void wtv_partial_kernel(
    const float4* __restrict__ W4, const float* __restrict__ hidden,
    float4* __restrict__ partial4)
{
    __shared__ float hs[RCHUNK];
    const int tx = threadIdx.x;
    const int h0 = blockIdx.y * RCHUNK;
    if (tx < RCHUNK) hs[tx] = hidden[h0 + tx];
    __syncthreads();

    const int c = blockIdx.x * 256 + tx;     // float4 column, 0..1023
    float4 acc = {0.f, 0.f, 0.f, 0.f};
#pragma unroll 8
    for (int i = 0; i < RCHUNK; ++i) {
        const float4 w = W4[(size_t)(h0 + i) * C4 + c];
        const float  s = hs[i];
        acc.x = fmaf(w.x, s, acc.x);
        acc.y = fmaf(w.y, s, acc.y);
        acc.z = fmaf(w.z, s, acc.z);
        acc.w = fmaf(w.w, s, acc.w);
    }
    partial4[(size_t)blockIdx.y * C4 + c] = acc;
}

// ---------------------------------------------------------------------------
// Kernel B: v = sum of 64 partials. Grid 4, block 256 (1024 float4 lanes).
// ---------------------------------------------------------------------------
__global__ __launch_bounds__(256) void wtv_reduce_kernel(
    const float4* __restrict__ partial4, float4* __restrict__ v4)
{
    const int c = blockIdx.x * 256 + threadIdx.x;
    float4 acc = {0.f, 0.f, 0.f, 0.f};
#pragma unroll
    for (int p = 0; p < NCHUNK; ++p) {
        const float4 t = partial4[(size_t)p * C4 + c];
        acc.x += t.x; acc.y += t.y; acc.z += t.z; acc.w += t.w;
    }
    v4[c] = acc;
}

// ---------------------------------------------------------------------------
// Kernel C: scores[r] = enc[r] . v   (row dot of length 4096)
// Grid 2048 blocks x 256 threads (4 waves); one wave per row.
// v staged in LDS as float4. No sync primitives beyond __syncthreads.
// ---------------------------------------------------------------------------
__global__ __launch_bounds__(256) void scores_kernel(
    const float4* __restrict__ enc4, const float4* __restrict__ v4,
    float* __restrict__ scores)
{
    __shared__ float4 vs[C4];                  // 16 KiB
    const int tid = threadIdx.x;
    for (int i = tid; i < C4; i += 256) vs[i] = v4[i];
    __syncthreads();

    const int wave = tid >> 6;
    const int lane = tid & 63;
    const int r    = blockIdx.x * 4 + wave;    // 0..8191

    const float4* e4 = enc4 + (size_t)r * C4;
    float a0 = 0.f, a1 = 0.f;
#pragma unroll
    for (int i = 0; i < 16; i += 2) {          // 16*64 float4 = 4096 floats
        const float4 x0 = e4[i * 64 + lane];
        const float4 b0 = vs[i * 64 + lane];
        const float4 x1 = e4[(i + 1) * 64 + lane];
        const float4 b1 = vs[(i + 1) * 64 + lane];
        a0 += x0.x * b0.x + x0.y * b0.y + x0.z * b0.z + x0.w * b0.w;
        a1 += x1.x * b1.x + x1.y * b1.y + x1.z * b1.z + x1.w * b1.w;
    }
    float acc = a0 + a1;
#pragma unroll
    for (int off = 32; off > 0; off >>= 1)
        acc += __shfl_down(acc, off, 64);
    if (lane == 0)
        scores[r] = acc;
}

// ---------------------------------------------------------------------------
// Kernel D: softmax over 8192 scores. One block of 1024 threads,
// 8 elements per thread (strided). Launch boundary = ordering.
// ---------------------------------------------------------------------------
__global__ __launch_bounds__(1024) void softmax_kernel(
    const float* __restrict__ scores, float* __restrict__ out)
{
    __shared__ float red[16];
    const int t    = threadIdx.x;
    const int wave = t >> 6;
    const int lane = t & 63;

    float x[8];
    float m = -INFINITY;
#pragma unroll
    for (int i = 0; i < 8; ++i) {
        x[i] = scores[t + i * 1024];
        m = fmaxf(m, x[i]);
    }
#pragma unroll
    for (int off = 32; off > 0; off >>= 1)
        m = fmaxf(m, __shfl_xor(m, off, 64));
    if (lane == 0) red[wave] = m;
    __syncthreads();
    float gmax = red[0];
#pragma unroll
    for (int w = 1; w < 16; ++w) gmax = fmaxf(gmax, red[w]);
    __syncthreads();                                 // before reusing red[]

    float s = 0.0f;
#pragma unroll
    for (int i = 0; i < 8; ++i) {
        x[i] = expf(x[i] - gmax);
        s += x[i];
    }
#pragma unroll
    for (int off = 32; off > 0; off >>= 1)
        s += __shfl_xor(s, off, 64);
    if (lane == 0) red[wave] = s;
    __syncthreads();
    float gsum = 0.0f;
#pragma unroll
    for (int w = 0; w < 16; ++w) gsum += red[w];

    const float inv = 1.0f / gsum;
#pragma unroll
    for (int i = 0; i < 8; ++i)
        out[t + i * 1024] = x[i] * inv;
}

// ---------------------------------------------------------------------------
extern "C" void kernel_launch(void* const* d_in, const int* in_sizes, int n_in,
                              void* d_out, int out_size, void* d_ws, size_t ws_size,
                              hipStream_t stream)
{
    const float* hidden = (const float*)d_in[0];   // [2048]
    const float* enc    = (const float*)d_in[1];   // [8192, 4096]
    const float* W      = (const float*)d_in[2];   // [2048, 4096]
    // d_in[3] = b : drops out under softmax shift-invariance

    float* ws      = (float*)d_ws;
    float* partial = ws;                            // 64 * 4096 floats (1 MiB)
    float* v       = partial + NCHUNK * TWOH;       // 4096
    float* scores  = v + TWOH;                      // 8192
    float* out     = (float*)d_out;                 // [8192] fp32

    wtv_partial_kernel<<<dim3(4, NCHUNK), 256, 0, stream>>>(
        (const float4*)W, hidden, (float4*)partial);
    wtv_reduce_kernel<<<4, 256, 0, stream>>>(
        (const float4*)partial, (float4*)v);
    scores_kernel<<<SEQLEN / 4, 256, 0, stream>>>(
        (const float4*)enc, (const float4*)v, scores);
    softmax_kernel<<<1, 1024, 0, stream>>>(scores, out);
}